// Round 7
// baseline (488.801 us; speedup 1.0000x reference)
//
#include <hip/hip_runtime.h>
#include <hip/hip_bf16.h>
#include <math.h>
#include <stdint.h>

typedef unsigned short u16;
typedef unsigned int u32;
typedef __bf16 bf16x2 __attribute__((ext_vector_type(2)));
typedef __bf16 bf16x8 __attribute__((ext_vector_type(8)));
typedef float f32x4 __attribute__((ext_vector_type(4)));

#define AS1 __attribute__((address_space(1)))
#define AS3 __attribute__((address_space(3)))

// Q pre-scale: 1/sqrt(64) * log2(e), so attention does p = exp2(S') = e^{S/8}
#define QSCALE 0.18033688011112042f

// ---------- helpers ----------
__device__ __forceinline__ u16 f2bf(float f) {  // RNE
  union { float f; u32 i; } c; c.f = f;
  const u32 x = c.i;
  return (u16)((x + 0x7fffu + ((x >> 16) & 1u)) >> 16);
}
#if __has_builtin(__builtin_amdgcn_cvt_pk_bf16_f32)
__device__ __forceinline__ u32 pkbf(float a, float b) {
  const bf16x2 v = __builtin_amdgcn_cvt_pk_bf16_f32(a, b);
  union { bf16x2 v; u32 i; } c; c.v = v; return c.i;
}
#else
__device__ __forceinline__ u32 pkbf(float a, float b) {
  return (u32)f2bf(a) | ((u32)f2bf(b) << 16);
}
#endif
#if __has_builtin(__builtin_amdgcn_exp2f)
#define EXP2(x) __builtin_amdgcn_exp2f(x)
#else
#define EXP2(x) __expf((x) * 0.6931471805599453f)
#endif
__device__ __forceinline__ void gload_lds16(const void* g, void* lds) {
  __builtin_amdgcn_global_load_lds((const AS1 void*)g, (AS3 void*)lds, 16, 0, 0);
}

// ---------- fused cast + mask check (one dispatch) ----------
// i < 2097152: x float4 -> bf16x4
// i < 3145728: weights (wq,wk,wv,wo)
// else       : mask int4 check -> atomicOr flag
__global__ void cast_all_kernel(const float* __restrict__ x, const float* __restrict__ wq,
                                const float* __restrict__ wk, const float* __restrict__ wv,
                                const float* __restrict__ wo, const int* __restrict__ mask,
                                u16* __restrict__ xh, u16* __restrict__ wh,
                                int* __restrict__ flag) {
  const int i = blockIdx.x * 256 + threadIdx.x;  // < 4194304
  if (i >= 3145728) {
    const int4 v = ((const int4*)mask)[i - 3145728];
    if (v.x == 0 || v.y == 0 || v.z == 0 || v.w == 0) atomicOr(flag, 1);
    return;
  }
  const float* src; u16* dst; int off;
  if (i < 2097152) {
    src = x; dst = xh; off = i;
  } else {
    const int j = i - 2097152;
    const int w = j >> 18;
    off = j & 262143;
    src = (w == 0) ? wq : (w == 1) ? wk : (w == 2) ? wv : wo;
    dst = wh + (size_t)w * 1048576;
  }
  const float4 v = ((const float4*)src)[off];
  ushort4 o;
  o.x = f2bf(v.x); o.y = f2bf(v.y); o.z = f2bf(v.z); o.w = f2bf(v.w);
  ((ushort4*)dst)[off] = o;
}

// ---------- GEMM: C[M,1024] = A[M,1024] @ W[1024,1024]^T + bias ----------
// Round-5 proven form (314.8us): 2-barrier BK=64 XOR-swizzled loop
// (conflicts 0), LDS hoisted to kernel scope (shared across MODE
// instantiations). Round-6's transposed epilogue regressed (-6.6us:
// uint2-per-lane at 128B stride = 1 cacheline/lane); original scalar
// stores are lane-contiguous along dk. Do not revisit.
// MODE 0: fp32 row-major out.
// MODE 1: bf16 scatter to [4][16][2048][64]  (Q, K: [bh][s][dk])
// MODE 2: bf16 to [4*16][64][2048] (V^T: [bh][dk][s]) — packed 8B stores.
// SCALE: multiply result by QSCALE (for Q).
// T1 XCD swizzle: each XCD owns contiguous m-panels (A 2MB + W 2MB fit L2).
template <int MODE, bool SCALE>
__device__ __forceinline__ void gemm_body(const u16* __restrict__ A,
                                          const u16* __restrict__ W,
                                          const float* __restrict__ bias,
                                          void* __restrict__ out,
                                          u16* __restrict__ As,
                                          u16* __restrict__ Bs) {
  const int tid = threadIdx.x;
  const int wave = tid >> 6, lane = tid & 63;
  const int quad = lane >> 4, l16 = lane & 15;
  // XCD-chunked bijective block swizzle (grid 8 x 64, nwg=512, 512%8==0)
  const int lid = blockIdx.y * 8 + blockIdx.x;
  const int flat = ((lid & 7) << 6) | (lid >> 3);
  const int m0 = (flat >> 3) * 128, n0 = (flat & 7) * 128;
  const int wm = (wave >> 1) * 64, wn = (wave & 1) * 64;

  f32x4 vzero = {0.f, 0.f, 0.f, 0.f};
  f32x4 acc[4][4];
#pragma unroll
  for (int i = 0; i < 4; i++)
#pragma unroll
    for (int j = 0; j < 4; j++) acc[i][j] = vzero;

  for (int k0 = 0; k0 < 1024; k0 += 64) {
    // stage [128 rows][64 cols] for A and W; 8 chunk-slots per row,
    // global chunk XOR-permuted (cc ^ (row&7)), LDS linear (rule #21).
#pragma unroll
    for (int p = 0; p < 4; ++p) {
      const int cbase = p * 256 + wave * 64;
      const int c = cbase + lane;
      const int row = c >> 3, cc = c & 7;
      const int gcol = k0 + ((cc ^ (row & 7)) << 3);
      gload_lds16(A + (size_t)(m0 + row) * 1024 + gcol, (char*)As + cbase * 16);
      gload_lds16(W + (size_t)(n0 + row) * 1024 + gcol, (char*)Bs + cbase * 16);
    }
    __syncthreads();
#pragma unroll
    for (int kk = 0; kk < 2; kk++) {
      bf16x8 af[4], bw[4];
#pragma unroll
      for (int im = 0; im < 4; im++) {
        const int r = wm + im * 16 + l16;
        af[im] = *(const bf16x8*)&As[r * 64 + (((kk * 4 + quad) ^ (l16 & 7)) << 3)];
      }
#pragma unroll
      for (int in_ = 0; in_ < 4; in_++) {
        const int r = wn + in_ * 16 + l16;
        bw[in_] = *(const bf16x8*)&Bs[r * 64 + (((kk * 4 + quad) ^ (l16 & 7)) << 3)];
      }
#pragma unroll
      for (int im = 0; im < 4; im++)
#pragma unroll
        for (int in_ = 0; in_ < 4; in_++)
          acc[im][in_] = __builtin_amdgcn_mfma_f32_16x16x32_bf16(af[im], bw[in_], acc[im][in_], 0, 0, 0);
    }
    __syncthreads();
  }

#pragma unroll
  for (int in_ = 0; in_ < 4; in_++) {
    const int col = n0 + wn + in_ * 16 + l16;
    const float bvf = bias[col];
    if (MODE == 2) {
      const int h = col >> 6, dk = col & 63;
#pragma unroll
      for (int im = 0; im < 4; im++) {
        const int row0 = m0 + wm + im * 16 + quad * 4;  // 4 consecutive s
        const int b = row0 >> 11, s = row0 & 2047;
        const u32 lo = pkbf(acc[im][in_][0] + bvf, acc[im][in_][1] + bvf);
        const u32 hi = pkbf(acc[im][in_][2] + bvf, acc[im][in_][3] + bvf);
        u16* base = (u16*)out + ((size_t)(b * 16 + h) * 64 + dk) * 2048 + s;
        uint2 pkd; pkd.x = lo; pkd.y = hi;
        *(uint2*)base = pkd;
      }
    } else {
#pragma unroll
      for (int im = 0; im < 4; im++) {
#pragma unroll
        for (int r = 0; r < 4; r++) {
          const int row = m0 + wm + im * 16 + quad * 4 + r;  // C/D: row=(lane>>4)*4+reg, col=lane&15
          float v = acc[im][in_][r] + bvf;
          if (SCALE) v *= QSCALE;
          if (MODE == 0) {
            ((float*)out)[(size_t)row * 1024 + col] = v;
          } else {  // MODE 1
            const int b = row >> 11, s = row & 2047;
            const int h = col >> 6, dk = col & 63;
            ((u16*)out)[((((size_t)b * 16 + h) * 2048) + s) * 64 + dk] = f2bf(v);
          }
        }
      }
    }
  }
}

__global__ __launch_bounds__(256) void gemm_qkv_kernel(
    const u16* __restrict__ x, const u16* __restrict__ wq, const u16* __restrict__ wk,
    const u16* __restrict__ wv, const float* __restrict__ bq, const float* __restrict__ bk,
    const float* __restrict__ bv, u16* __restrict__ Q, u16* __restrict__ K,
    u16* __restrict__ VT) {
  __shared__ alignas(16) u16 As[128 * 64];
  __shared__ alignas(16) u16 Bs[128 * 64];
  if (blockIdx.z == 0)      gemm_body<1, true >(x, wq, bq, Q, As, Bs);
  else if (blockIdx.z == 1) gemm_body<1, false>(x, wk, bk, K, As, Bs);
  else                      gemm_body<2, false>(x, wv, bv, VT, As, Bs);
}

__global__ __launch_bounds__(256) void gemm_o_kernel(const u16* __restrict__ A,
                                                     const u16* __restrict__ wo,
                                                     const float* __restrict__ bo,
                                                     float* __restrict__ out) {
  __shared__ alignas(16) u16 As[128 * 64];
  __shared__ alignas(16) u16 Bs[128 * 64];
  gemm_body<0, false>(A, wo, bo, out, As, Bs);
}

// ---------- flash attention v7: barrier-free, K/V direct from L2 ----------
// Since T1 swizzle, attn FETCH=24.6MB => each XCD's 8 heads of K/V (4MB) are
// L2-resident. Guide common-mistake #7 (m169, +26%): LDS-staging cache-fit
// data is pure overhead. K [key][dk] and V^T [dk][key] are both 16B-
// contiguous along the MFMA fragment's k-chunk dim, so B-fragments load
// DIRECTLY from global (L1/L2). Ks/Vt staging + BOTH per-iter barriers
// removed (P is per-wave LDS; waves fully independent) -> attacks the ~32%
// neither-pipe-issues stall + halves DS traffic. LDS 16KB.
__global__ __launch_bounds__(256) void attn_kernel(const u16* __restrict__ Q,
                                                   const u16* __restrict__ K,
                                                   const u16* __restrict__ VT,
                                                   const int* __restrict__ mask,
                                                   const int* __restrict__ flag,
                                                   u16* __restrict__ O) {
  __shared__ alignas(16) u16 Ps[4 * 2048];  // per-wave [32 q][64 key] swizzled

  const int tid = threadIdx.x;
  const int wave = tid >> 6, lane = tid & 63;
  const int quad = lane >> 4, l16 = lane & 15;
  // XCD-chunked bijective swizzle (grid 16 x 64, nwg=1024, 1024%8==0):
  // each XCD gets 8 contiguous bh (8x512KB K/V = 4MB = its L2).
  const int lid = blockIdx.y * 16 + blockIdx.x;
  const int flat = ((lid & 7) << 7) | (lid >> 3);
  const int qt_ = flat & 15, bh = flat >> 4;
  const int b = bh >> 4, h = bh & 15;
  const int q0 = qt_ * 128;
  const u16* Qh = Q + (size_t)bh * 2048 * 64;
  const u16* Kh = K + (size_t)bh * 2048 * 64;
  const u16* Vth = VT + (size_t)bh * 64 * 2048;
  u16* Pw = Ps + wave * 2048;
  const bool masked = (*flag != 0);

  // Q fragments for 2 q-tiles (A-layout: A[m=l16][k=quad*8+j]).
  bf16x8 aq[2][2];
#pragma unroll
  for (int qt = 0; qt < 2; qt++) {
    const u16* qrow = Qh + (size_t)(q0 + qt * 64 + wave * 16 + l16) * 64 + quad * 8;
    aq[qt][0] = *(const bf16x8*)qrow;
    aq[qt][1] = *(const bf16x8*)(qrow + 32);
  }

  f32x4 vzero = {0.f, 0.f, 0.f, 0.f};
  f32x4 acc[2][4];
#pragma unroll
  for (int qt = 0; qt < 2; qt++)
#pragma unroll
    for (int jd = 0; jd < 4; jd++) acc[qt][jd] = vzero;
  float lp[2][4] = {{0.f, 0.f, 0.f, 0.f}, {0.f, 0.f, 0.f, 0.f}};

  for (int kb = 0; kb < 32; ++kb) {
    const int key0 = kb * 64;

    // scores S' = Q' K^T; K fragments straight from global (L2-hot).
    // B-frag: row = key (16 lanes = 16 keys, stride 128B), k-chunk = 16B
    // contiguous along dk. Shared bk read feeds both q-tiles.
#pragma unroll
    for (int jn = 0; jn < 4; jn++) {
      f32x4 sc0 = vzero, sc1 = vzero;
      __builtin_amdgcn_s_setprio(1);
#pragma unroll
      for (int kc = 0; kc < 2; kc++) {
        const int r_ = jn * 16 + l16;
        const bf16x8 bk_ = *(const bf16x8*)
            (Kh + (size_t)(key0 + r_) * 64 + (kc * 4 + quad) * 8);
        sc0 = __builtin_amdgcn_mfma_f32_16x16x32_bf16(aq[0][kc], bk_, sc0, 0, 0, 0);
        sc1 = __builtin_amdgcn_mfma_f32_16x16x32_bf16(aq[1][kc], bk_, sc1, 0, 0, 0);
      }
      __builtin_amdgcn_s_setprio(0);
      if (masked) {
#pragma unroll
        for (int r = 0; r < 4; r++) {
          const int kg = key0 + jn * 16 + l16;
          const int qa = q0 + wave * 16 + quad * 4 + r;
          if (mask[(size_t)qa * 2048 + kg] == 0) sc0[r] = -INFINITY;
          if (mask[(size_t)(qa + 64) * 2048 + kg] == 0) sc1[r] = -INFINITY;
        }
      }
      float pe0[4], pe1[4];
#pragma unroll
      for (int r = 0; r < 4; r++) {
        pe0[r] = EXP2(sc0[r]); lp[0][r] += pe0[r];
        pe1[r] = EXP2(sc1[r]); lp[1][r] += pe1[r];
      }
      // P -> per-wave LDS (C-layout -> A-layout), swizzled, packed pairs
#pragma unroll
      for (int r = 0; r < 4; r += 2) {
        const u32 pk0 = pkbf(pe0[r], pe0[r + 1]);
        const u32 pk1 = pkbf(pe1[r], pe1[r + 1]);
        const int qa = quad * 4 + r, qb = qa + 1;
        const int sw = jn * 2 + (l16 >> 3), lo3 = l16 & 7;
        Pw[qa * 64 + (((sw ^ (qa & 7)) << 3)) + lo3] = (u16)pk0;
        Pw[qb * 64 + (((sw ^ (qb & 7)) << 3)) + lo3] = (u16)(pk0 >> 16);
        Pw[(16 + qa) * 64 + (((sw ^ (qa & 7)) << 3)) + lo3] = (u16)pk1;
        Pw[(16 + qb) * 64 + (((sw ^ (qb & 7)) << 3)) + lo3] = (u16)(pk1 >> 16);
      }
    }

    // O += P @ V ; V^T fragments straight from global (L2-hot).
    bf16x8 ap0[2], ap1[2];
#pragma unroll
    for (int kc = 0; kc < 2; kc++) {
      ap0[kc] = *(const bf16x8*)&Pw[l16 * 64 + (((kc * 4 + quad) ^ (l16 & 7)) << 3)];
      ap1[kc] = *(const bf16x8*)&Pw[(16 + l16) * 64 + (((kc * 4 + quad) ^ (l16 & 7)) << 3)];
    }
    __builtin_amdgcn_s_setprio(1);
#pragma unroll
    for (int jd = 0; jd < 4; jd++) {
#pragma unroll
      for (int kc = 0; kc < 2; kc++) {
        const int dk_ = jd * 16 + l16;
        const bf16x8 bv_ = *(const bf16x8*)
            (Vth + (size_t)dk_ * 2048 + key0 + (kc * 4 + quad) * 8);
        acc[0][jd] = __builtin_amdgcn_mfma_f32_16x16x32_bf16(ap0[kc], bv_, acc[0][jd], 0, 0, 0);
        acc[1][jd] = __builtin_amdgcn_mfma_f32_16x16x32_bf16(ap1[kc], bv_, acc[1][jd], 0, 0, 0);
      }
    }
    __builtin_amdgcn_s_setprio(0);
    // no barrier: Ps is per-wave; compiler inserts lgkmcnt for the
    // Pw write->read (this iter) and read->overwrite (next iter) hazards.
  }

  // epilogue: reduce l across the 16 lanes of each quad, divide, store
#pragma unroll
  for (int qt = 0; qt < 2; qt++) {
#pragma unroll
    for (int r = 0; r < 4; r++) {
      float ls = lp[qt][r];
#pragma unroll
      for (int off = 1; off < 16; off <<= 1) ls += __shfl_xor(ls, off, 16);
      const float linv = 1.0f / ls;
      const int qg = q0 + qt * 64 + wave * 16 + quad * 4 + r;
      const size_t token = (size_t)b * 2048 + qg;
#pragma unroll
      for (int jd = 0; jd < 4; jd++) {
        const int col = h * 64 + jd * 16 + l16;
        O[token * 1024 + col] = f2bf(acc[qt][jd][r] * linv);
      }
    }
  }
}

// ---------- launch ----------
extern "C" void kernel_launch(void* const* d_in, const int* in_sizes, int n_in,
                              void* d_out, int out_size, void* d_ws, size_t ws_size,
                              hipStream_t stream) {
  const float* x  = (const float*)d_in[0];
  const int* mask = (const int*)d_in[1];
  const float* wq = (const float*)d_in[2];
  const float* bq = (const float*)d_in[3];
  const float* wk = (const float*)d_in[4];
  const float* bk = (const float*)d_in[5];
  const float* wv = (const float*)d_in[6];
  const float* bv = (const float*)d_in[7];
  const float* wo = (const float*)d_in[8];
  const float* bo = (const float*)d_in[9];
  float* out = (float*)d_out;

  // ws layout (u16 units). xh region is reused as Ow after gemm_qkv consumes it.
  u16* xh = (u16*)d_ws;                 // 8388608 elems -> later Ow
  u16* wh = xh + 8388608;               // 4 x 1048576: wq,wk,wv,wo (bf16)
  u16* Qw = wh + 4194304;               // 8388608 (pre-scaled by QSCALE)
  u16* Kw = Qw + 8388608;
  u16* Vw = Kw + 8388608;               // holds V^T [bh][dk][s]
  int* mflag = (int*)(Vw + 8388608);
  u16* Ow = xh;

  hipMemsetAsync(mflag, 0, sizeof(int), stream);
  cast_all_kernel<<<16384, 256, 0, stream>>>(x, wq, wk, wv, wo, mask, xh, wh, mflag);

  gemm_qkv_kernel<<<dim3(8, 64, 3), 256, 0, stream>>>(
      xh, wh + 0 * 1048576, wh + 1 * 1048576, wh + 2 * 1048576,
      bq, bk, bv, Qw, Kw, Vw);
  attn_kernel<<<dim3(16, 64), 256, 0, stream>>>(Qw, Kw, Vw, mask, mflag, Ow);
  gemm_o_kernel<<<dim3(8, 64, 1), 256, 0, stream>>>(Ow, wh + 3 * 1048576, bo, out);
}

// Round 8
// 301.531 us; speedup vs baseline: 1.6211x; 1.6211x over previous
//
#include <hip/hip_runtime.h>
#include <hip/hip_bf16.h>
#include <math.h>
#include <stdint.h>

typedef unsigned short u16;
typedef unsigned int u32;
typedef __bf16 bf16x2 __attribute__((ext_vector_type(2)));
typedef __bf16 bf16x8 __attribute__((ext_vector_type(8)));
typedef float f32x4 __attribute__((ext_vector_type(4)));

#define AS1 __attribute__((address_space(1)))
#define AS3 __attribute__((address_space(3)))

// Q pre-scale: 1/sqrt(64) * log2(e), so attention does p = exp2(S') = e^{S/8}
#define QSCALE 0.18033688011112042f

// ---------- helpers ----------
__device__ __forceinline__ u16 f2bf(float f) {  // RNE
  union { float f; u32 i; } c; c.f = f;
  const u32 x = c.i;
  return (u16)((x + 0x7fffu + ((x >> 16) & 1u)) >> 16);
}
#if __has_builtin(__builtin_amdgcn_cvt_pk_bf16_f32)
__device__ __forceinline__ u32 pkbf(float a, float b) {
  const bf16x2 v = __builtin_amdgcn_cvt_pk_bf16_f32(a, b);
  union { bf16x2 v; u32 i; } c; c.v = v; return c.i;
}
#else
__device__ __forceinline__ u32 pkbf(float a, float b) {
  return (u32)f2bf(a) | ((u32)f2bf(b) << 16);
}
#endif
#if __has_builtin(__builtin_amdgcn_exp2f)
#define EXP2(x) __builtin_amdgcn_exp2f(x)
#else
#define EXP2(x) __expf((x) * 0.6931471805599453f)
#endif
__device__ __forceinline__ void gload_lds16(const void* g, void* lds) {
  __builtin_amdgcn_global_load_lds((const AS1 void*)g, (AS3 void*)lds, 16, 0, 0);
}

// ---------- fused cast + mask check (one dispatch) ----------
// i < 2097152: x float4 -> bf16x4
// i < 3145728: weights (wq,wk,wv,wo)
// else       : mask int4 check -> atomicOr flag
__global__ void cast_all_kernel(const float* __restrict__ x, const float* __restrict__ wq,
                                const float* __restrict__ wk, const float* __restrict__ wv,
                                const float* __restrict__ wo, const int* __restrict__ mask,
                                u16* __restrict__ xh, u16* __restrict__ wh,
                                int* __restrict__ flag) {
  const int i = blockIdx.x * 256 + threadIdx.x;  // < 4194304
  if (i >= 3145728) {
    const int4 v = ((const int4*)mask)[i - 3145728];
    if (v.x == 0 || v.y == 0 || v.z == 0 || v.w == 0) atomicOr(flag, 1);
    return;
  }
  const float* src; u16* dst; int off;
  if (i < 2097152) {
    src = x; dst = xh; off = i;
  } else {
    const int j = i - 2097152;
    const int w = j >> 18;
    off = j & 262143;
    src = (w == 0) ? wq : (w == 1) ? wk : (w == 2) ? wv : wo;
    dst = wh + (size_t)w * 1048576;
  }
  const float4 v = ((const float4*)src)[off];
  ushort4 o;
  o.x = f2bf(v.x); o.y = f2bf(v.y); o.z = f2bf(v.z); o.w = f2bf(v.w);
  ((ushort4*)dst)[off] = o;
}

// ---------- GEMM: C[M,1024] = A[M,1024] @ W[1024,1024]^T + bias ----------
// Round-5 proven form (314.8us): 2-barrier BK=64 XOR-swizzled loop
// (conflicts 0), LDS hoisted to kernel scope (shared across MODE
// instantiations). Round-8 adds __launch_bounds__(256,4): VGPR was 132
// (3 blocks/CU); capping at 128 -> 4 blocks/CU (+33% waves to hide the
// staging drain). History: dbuf pipeline -28% (R3, aliasing serialization);
// transposed epilogue -7us (R6, 1 cacheline/lane) -- do not revisit either.
// MODE 0: fp32 row-major out.
// MODE 1: bf16 scatter to [4][16][2048][64]  (Q, K: [bh][s][dk])
// MODE 2: bf16 to [4*16][64][2048] (V^T: [bh][dk][s]) — packed 8B stores.
// SCALE: multiply result by QSCALE (for Q).
// T1 XCD swizzle: each XCD owns contiguous m-panels (A 2MB + W 2MB fit L2).
template <int MODE, bool SCALE>
__device__ __forceinline__ void gemm_body(const u16* __restrict__ A,
                                          const u16* __restrict__ W,
                                          const float* __restrict__ bias,
                                          void* __restrict__ out,
                                          u16* __restrict__ As,
                                          u16* __restrict__ Bs) {
  const int tid = threadIdx.x;
  const int wave = tid >> 6, lane = tid & 63;
  const int quad = lane >> 4, l16 = lane & 15;
  // XCD-chunked bijective block swizzle (grid 8 x 64, nwg=512, 512%8==0)
  const int lid = blockIdx.y * 8 + blockIdx.x;
  const int flat = ((lid & 7) << 6) | (lid >> 3);
  const int m0 = (flat >> 3) * 128, n0 = (flat & 7) * 128;
  const int wm = (wave >> 1) * 64, wn = (wave & 1) * 64;

  f32x4 vzero = {0.f, 0.f, 0.f, 0.f};
  f32x4 acc[4][4];
#pragma unroll
  for (int i = 0; i < 4; i++)
#pragma unroll
    for (int j = 0; j < 4; j++) acc[i][j] = vzero;

  for (int k0 = 0; k0 < 1024; k0 += 64) {
    // stage [128 rows][64 cols] for A and W; 8 chunk-slots per row,
    // global chunk XOR-permuted (cc ^ (row&7)), LDS linear (rule #21).
#pragma unroll
    for (int p = 0; p < 4; ++p) {
      const int cbase = p * 256 + wave * 64;
      const int c = cbase + lane;
      const int row = c >> 3, cc = c & 7;
      const int gcol = k0 + ((cc ^ (row & 7)) << 3);
      gload_lds16(A + (size_t)(m0 + row) * 1024 + gcol, (char*)As + cbase * 16);
      gload_lds16(W + (size_t)(n0 + row) * 1024 + gcol, (char*)Bs + cbase * 16);
    }
    __syncthreads();
#pragma unroll
    for (int kk = 0; kk < 2; kk++) {
      bf16x8 af[4], bw[4];
#pragma unroll
      for (int im = 0; im < 4; im++) {
        const int r = wm + im * 16 + l16;
        af[im] = *(const bf16x8*)&As[r * 64 + (((kk * 4 + quad) ^ (l16 & 7)) << 3)];
      }
#pragma unroll
      for (int in_ = 0; in_ < 4; in_++) {
        const int r = wn + in_ * 16 + l16;
        bw[in_] = *(const bf16x8*)&Bs[r * 64 + (((kk * 4 + quad) ^ (l16 & 7)) << 3)];
      }
#pragma unroll
      for (int im = 0; im < 4; im++)
#pragma unroll
        for (int in_ = 0; in_ < 4; in_++)
          acc[im][in_] = __builtin_amdgcn_mfma_f32_16x16x32_bf16(af[im], bw[in_], acc[im][in_], 0, 0, 0);
    }
    __syncthreads();
  }

#pragma unroll
  for (int in_ = 0; in_ < 4; in_++) {
    const int col = n0 + wn + in_ * 16 + l16;
    const float bvf = bias[col];
    if (MODE == 2) {
      const int h = col >> 6, dk = col & 63;
#pragma unroll
      for (int im = 0; im < 4; im++) {
        const int row0 = m0 + wm + im * 16 + quad * 4;  // 4 consecutive s
        const int b = row0 >> 11, s = row0 & 2047;
        const u32 lo = pkbf(acc[im][in_][0] + bvf, acc[im][in_][1] + bvf);
        const u32 hi = pkbf(acc[im][in_][2] + bvf, acc[im][in_][3] + bvf);
        u16* base = (u16*)out + ((size_t)(b * 16 + h) * 64 + dk) * 2048 + s;
        uint2 pkd; pkd.x = lo; pkd.y = hi;
        *(uint2*)base = pkd;
      }
    } else {
#pragma unroll
      for (int im = 0; im < 4; im++) {
#pragma unroll
        for (int r = 0; r < 4; r++) {
          const int row = m0 + wm + im * 16 + quad * 4 + r;  // C/D: row=(lane>>4)*4+reg, col=lane&15
          float v = acc[im][in_][r] + bvf;
          if (SCALE) v *= QSCALE;
          if (MODE == 0) {
            ((float*)out)[(size_t)row * 1024 + col] = v;
          } else {  // MODE 1
            const int b = row >> 11, s = row & 2047;
            const int h = col >> 6, dk = col & 63;
            ((u16*)out)[((((size_t)b * 16 + h) * 2048) + s) * 64 + dk] = f2bf(v);
          }
        }
      }
    }
  }
}

__global__ __launch_bounds__(256, 4) void gemm_qkv_kernel(
    const u16* __restrict__ x, const u16* __restrict__ wq, const u16* __restrict__ wk,
    const u16* __restrict__ wv, const float* __restrict__ bq, const float* __restrict__ bk,
    const float* __restrict__ bv, u16* __restrict__ Q, u16* __restrict__ K,
    u16* __restrict__ VT) {
  __shared__ alignas(16) u16 As[128 * 64];
  __shared__ alignas(16) u16 Bs[128 * 64];
  if (blockIdx.z == 0)      gemm_body<1, true >(x, wq, bq, Q, As, Bs);
  else if (blockIdx.z == 1) gemm_body<1, false>(x, wk, bk, K, As, Bs);
  else                      gemm_body<2, false>(x, wv, bv, VT, As, Bs);
}

__global__ __launch_bounds__(256, 4) void gemm_o_kernel(const u16* __restrict__ A,
                                                        const u16* __restrict__ wo,
                                                        const float* __restrict__ bo,
                                                        float* __restrict__ out) {
  __shared__ alignas(16) u16 As[128 * 64];
  __shared__ alignas(16) u16 Bs[128 * 64];
  gemm_body<0, false>(A, wo, bo, out, As, Bs);
}

// ---------- flash attention v6 (restored: validated 123.5-125.5us) ----------
// LDS/VALU/DS-throughput-bound (MfmaUtil 23, VALUBusy 45, FETCH 24.6MB after
// T1 swizzle, conflicts 0, 5 blocks/CU). Failed attacks, do not revisit:
// K-dbuf pipeline (R1: LDS 40KB -> 4 blocks/CU, -6%); direct-from-L2
// fragment reads (R7: 16-lane scatter across cachelines, -140%). Staging is
// load-shape conversion, not caching.
__global__ __launch_bounds__(256) void attn_kernel(const u16* __restrict__ Q,
                                                   const u16* __restrict__ K,
                                                   const u16* __restrict__ VT,
                                                   const int* __restrict__ mask,
                                                   const int* __restrict__ flag,
                                                   u16* __restrict__ O) {
  __shared__ alignas(16) u16 Ks[64 * 64];   // [key][dk] swizzled
  __shared__ alignas(16) u16 Vt[64 * 64];   // [dk][key] swizzled
  __shared__ alignas(16) u16 Ps[4 * 2048];  // per-wave [32 q][64 key] swizzled

  const int tid = threadIdx.x;
  const int wave = tid >> 6, lane = tid & 63;
  const int quad = lane >> 4, l16 = lane & 15;
  // XCD-chunked bijective swizzle (grid 16 x 64, nwg=1024, 1024%8==0):
  // each XCD gets 8 contiguous bh (8x512KB K/V = 4MB = its L2).
  const int lid = blockIdx.y * 16 + blockIdx.x;
  const int flat = ((lid & 7) << 7) | (lid >> 3);
  const int qt_ = flat & 15, bh = flat >> 4;
  const int b = bh >> 4, h = bh & 15;
  const int q0 = qt_ * 128;
  const u16* Qh = Q + (size_t)bh * 2048 * 64;
  const u16* Kh = K + (size_t)bh * 2048 * 64;
  const u16* Vth = VT + (size_t)bh * 64 * 2048;
  u16* Pw = Ps + wave * 2048;
  const bool masked = (*flag != 0);

  // Q fragments for 2 q-tiles (A-layout: A[m=l16][k=quad*8+j]).
  bf16x8 aq[2][2];
#pragma unroll
  for (int qt = 0; qt < 2; qt++) {
    const u16* qrow = Qh + (size_t)(q0 + qt * 64 + wave * 16 + l16) * 64 + quad * 8;
    aq[qt][0] = *(const bf16x8*)qrow;
    aq[qt][1] = *(const bf16x8*)(qrow + 32);
  }

  f32x4 vzero = {0.f, 0.f, 0.f, 0.f};
  f32x4 acc[2][4];
#pragma unroll
  for (int qt = 0; qt < 2; qt++)
#pragma unroll
    for (int jd = 0; jd < 4; jd++) acc[qt][jd] = vzero;
  float lp[2][4] = {{0.f, 0.f, 0.f, 0.f}, {0.f, 0.f, 0.f, 0.f}};

  for (int kb = 0; kb < 32; ++kb) {
    const int key0 = kb * 64;
    // stage K rows + V^T rows: swizzled global_load_lds, 16B/lane
#pragma unroll
    for (int p = 0; p < 2; ++p) {
      const int cbase = p * 256 + wave * 64;
      const int c = cbase + lane;
      const int row = c >> 3, cc = c & 7;
      gload_lds16(Kh + (size_t)(key0 + row) * 64 + ((cc ^ (row & 7)) << 3),
                  (char*)Ks + cbase * 16);
      gload_lds16(Vth + (size_t)row * 2048 + key0 + ((cc ^ (row & 7)) << 3),
                  (char*)Vt + cbase * 16);
    }
    __syncthreads();

    // scores S' = Q' K^T; p = exp2(S'); shared bk read feeds both q-tiles
#pragma unroll
    for (int jn = 0; jn < 4; jn++) {
      f32x4 sc0 = vzero, sc1 = vzero;
      __builtin_amdgcn_s_setprio(1);
#pragma unroll
      for (int kc = 0; kc < 2; kc++) {
        const int r_ = jn * 16 + l16;
        const bf16x8 bk_ = *(const bf16x8*)
            &Ks[r_ * 64 + (((kc * 4 + quad) ^ (l16 & 7)) << 3)];
        sc0 = __builtin_amdgcn_mfma_f32_16x16x32_bf16(aq[0][kc], bk_, sc0, 0, 0, 0);
        sc1 = __builtin_amdgcn_mfma_f32_16x16x32_bf16(aq[1][kc], bk_, sc1, 0, 0, 0);
      }
      __builtin_amdgcn_s_setprio(0);
      if (masked) {
#pragma unroll
        for (int r = 0; r < 4; r++) {
          const int kg = key0 + jn * 16 + l16;
          const int qa = q0 + wave * 16 + quad * 4 + r;
          if (mask[(size_t)qa * 2048 + kg] == 0) sc0[r] = -INFINITY;
          if (mask[(size_t)(qa + 64) * 2048 + kg] == 0) sc1[r] = -INFINITY;
        }
      }
      float pe0[4], pe1[4];
#pragma unroll
      for (int r = 0; r < 4; r++) {
        pe0[r] = EXP2(sc0[r]); lp[0][r] += pe0[r];
        pe1[r] = EXP2(sc1[r]); lp[1][r] += pe1[r];
      }
      // P -> per-wave LDS (C-layout -> A-layout), swizzled, packed pairs
#pragma unroll
      for (int r = 0; r < 4; r += 2) {
        const u32 pk0 = pkbf(pe0[r], pe0[r + 1]);
        const u32 pk1 = pkbf(pe1[r], pe1[r + 1]);
        const int qa = quad * 4 + r, qb = qa + 1;
        const int sw = jn * 2 + (l16 >> 3), lo3 = l16 & 7;
        Pw[qa * 64 + (((sw ^ (qa & 7)) << 3)) + lo3] = (u16)pk0;
        Pw[qb * 64 + (((sw ^ (qb & 7)) << 3)) + lo3] = (u16)(pk0 >> 16);
        Pw[(16 + qa) * 64 + (((sw ^ (qa & 7)) << 3)) + lo3] = (u16)pk1;
        Pw[(16 + qb) * 64 + (((sw ^ (qb & 7)) << 3)) + lo3] = (u16)(pk1 >> 16);
      }
    }

    // O += P @ V ; shared bv read feeds both q-tiles
    bf16x8 ap0[2], ap1[2];
#pragma unroll
    for (int kc = 0; kc < 2; kc++) {
      ap0[kc] = *(const bf16x8*)&Pw[l16 * 64 + (((kc * 4 + quad) ^ (l16 & 7)) << 3)];
      ap1[kc] = *(const bf16x8*)&Pw[(16 + l16) * 64 + (((kc * 4 + quad) ^ (l16 & 7)) << 3)];
    }
    __builtin_amdgcn_s_setprio(1);
#pragma unroll
    for (int jd = 0; jd < 4; jd++) {
#pragma unroll
      for (int kc = 0; kc < 2; kc++) {
        const int dk_ = jd * 16 + l16;
        const bf16x8 bv_ = *(const bf16x8*)
            &Vt[dk_ * 64 + (((kc * 4 + quad) ^ (l16 & 7)) << 3)];
        acc[0][jd] = __builtin_amdgcn_mfma_f32_16x16x32_bf16(ap0[kc], bv_, acc[0][jd], 0, 0, 0);
        acc[1][jd] = __builtin_amdgcn_mfma_f32_16x16x32_bf16(ap1[kc], bv_, acc[1][jd], 0, 0, 0);
      }
    }
    __builtin_amdgcn_s_setprio(0);
    __syncthreads();
  }

  // epilogue: reduce l across the 16 lanes of each quad, divide, store
#pragma unroll
  for (int qt = 0; qt < 2; qt++) {
#pragma unroll
    for (int r = 0; r < 4; r++) {
      float ls = lp[qt][r];
#pragma unroll
      for (int off = 1; off < 16; off <<= 1) ls += __shfl_xor(ls, off, 16);
      const float linv = 1.0f / ls;
      const int qg = q0 + qt * 64 + wave * 16 + quad * 4 + r;
      const size_t token = (size_t)b * 2048 + qg;
#pragma unroll
      for (int jd = 0; jd < 4; jd++) {
        const int col = h * 64 + jd * 16 + l16;
        O[token * 1024 + col] = f2bf(acc[qt][jd][r] * linv);
      }
    }
  }
}

// ---------- launch ----------
extern "C" void kernel_launch(void* const* d_in, const int* in_sizes, int n_in,
                              void* d_out, int out_size, void* d_ws, size_t ws_size,
                              hipStream_t stream) {
  const float* x  = (const float*)d_in[0];
  const int* mask = (const int*)d_in[1];
  const float* wq = (const float*)d_in[2];
  const float* bq = (const float*)d_in[3];
  const float* wk = (const float*)d_in[4];
  const float* bk = (const float*)d_in[5];
  const float* wv = (const float*)d_in[6];
  const float* bv = (const float*)d_in[7];
  const float* wo = (const float*)d_in[8];
  const float* bo = (const float*)d_in[9];
  float* out = (float*)d_out;

  // ws layout (u16 units). xh region is reused as Ow after gemm_qkv consumes it.
  u16* xh = (u16*)d_ws;                 // 8388608 elems -> later Ow
  u16* wh = xh + 8388608;               // 4 x 1048576: wq,wk,wv,wo (bf16)
  u16* Qw = wh + 4194304;               // 8388608 (pre-scaled by QSCALE)
  u16* Kw = Qw + 8388608;
  u16* Vw = Kw + 8388608;               // holds V^T [bh][dk][s]
  int* mflag = (int*)(Vw + 8388608);
  u16* Ow = xh;

  hipMemsetAsync(mflag, 0, sizeof(int), stream);
  cast_all_kernel<<<16384, 256, 0, stream>>>(x, wq, wk, wv, wo, mask, xh, wh, mflag);

  gemm_qkv_kernel<<<dim3(8, 64, 3), 256, 0, stream>>>(
      xh, wh + 0 * 1048576, wh + 1 * 1048576, wh + 2 * 1048576,
      bq, bk, bv, Qw, Kw, Vw);
  attn_kernel<<<dim3(16, 64), 256, 0, stream>>>(Qw, Kw, Vw, mask, mflag, Ow);
  gemm_o_kernel<<<dim3(8, 64, 1), 256, 0, stream>>>(Ow, wh + 3 * 1048576, bo, out);
}